// Round 2
// baseline (316.500 us; speedup 1.0000x reference)
//
#include <hip/hip_runtime.h>

// RPN proposal selector: softmax-score -> threshold -> greedy NMS (top-100)
// -> small-box filter -> scale to fraction-of-image.
//
// Equivalence used: reference's scan of {argmax over active; suppress iou>thr}
// == process candidates in (score desc, idx asc) order, keep iff iou<=thr vs
// all previously-kept. Ties break to the LOWEST original index (jnp.argmax
// first-occurrence), preserved at every reduction level below.
//
// Phase 2 is a single-wave latency-bound serial loop; all per-pop state
// (group argmax score/idx/box) lives in LDS so the pop path never touches
// global memory. Suppression history lives in the global `active` array
// (store issued off the critical path; visible by the next pop via the
// compiler's pre-barrier vmcnt(0) drain; the immediate rescan masks the
// popped idx by lane-compare instead).

#define CLS_THR 0.7f
#define NMS_THR 0.7f
#define MAX_OUT 100
#define MIN_SZ  3.0f

#define N_CAP   147456                 // B*H*W*A for this problem
#define G_CAP   ((N_CAP + 63) / 64)    // 2304 groups of 64
#define SG_CAP  ((G_CAP + 63) / 64)    // 36 supergroups of 64 groups

// ---------------------------------------------------------------------------
// Phase 1: per-box score = softmax(cls pair)[0]; active = score if >thr else -1.
// Emits per-64-box group records: (max score, argmax idx, argmax box coords),
// first-occurrence (lowest-index) tie-breaking.
// ---------------------------------------------------------------------------
__global__ void score_groups_kernel(const float4* __restrict__ boxes,
                                    const float2* __restrict__ cls,
                                    float* __restrict__ active,
                                    float* __restrict__ gs, int* __restrict__ gi,
                                    float4* __restrict__ gbox,
                                    int N) {
    int i = blockIdx.x * blockDim.x + threadIdx.x;
    float  s = -2.0f;                   // pad sentinel < -1 so real -1 wins
    float4 b = make_float4(0.f, 0.f, 0.f, 0.f);
    if (i < N) {
        float2 l = cls[i];
        // match jax.nn.softmax numerics: exp(x - max) / sum
        float m  = fmaxf(l.x, l.y);
        float e0 = expf(l.x - m);
        float e1 = expf(l.y - m);
        float p  = e0 / (e0 + e1);
        s = (p > CLS_THR) ? p : -1.0f;
        active[i] = s;
        b = boxes[i];
    }
    // wave-64 argmax, tie -> lower index
    float bs = s; int bi = i;
    #pragma unroll
    for (int off = 32; off > 0; off >>= 1) {
        float os = __shfl_down(bs, off);
        int   oi = __shfl_down(bi, off);
        if (os > bs || (os == bs && oi < bi)) { bs = os; bi = oi; }
    }
    // broadcast winner idx, pull its coords from the owning lane
    int wsrc = __shfl(bi, 0) & 63;
    float wy1 = __shfl(b.x, wsrc);
    float wx1 = __shfl(b.y, wsrc);
    float wy2 = __shfl(b.z, wsrc);
    float wx2 = __shfl(b.w, wsrc);
    if ((threadIdx.x & 63) == 0 && i < N) {
        int g = i >> 6;
        gs[g] = bs; gi[g] = bi;
        gbox[g] = make_float4(wy1, wx1, wy2, wx2);
    }
}

// ---------------------------------------------------------------------------
// Phase 2: single-wave lazy NMS over a 3-level max hierarchy, all in LDS.
// ---------------------------------------------------------------------------
__launch_bounds__(64)
__global__ void nms_kernel(const float4* __restrict__ boxes,
                           float* active,                       // no restrict: we store+load
                           const float* __restrict__ ggs, const int* __restrict__ ggi,
                           const float4* __restrict__ ggbox,
                           const int* __restrict__ ph, const int* __restrict__ pw,
                           float* __restrict__ out, int N) {
    __shared__ float  g_s[G_CAP];
    __shared__ int    g_i[G_CAP];
    __shared__ float4 g_b[G_CAP];
    __shared__ float  sg_s[SG_CAP];
    __shared__ int    sg_g[SG_CAP];
    __shared__ float kb_y1[MAX_OUT], kb_x1[MAX_OUT], kb_y2[MAX_OUT],
                     kb_x2[MAX_OUT], kb_a[MAX_OUT];

    const int lane     = threadIdx.x;
    const int n_groups = (N + 63) >> 6;
    const int n_sg     = (n_groups + 63) >> 6;
    const float img_h  = (float)(*ph);
    const float img_w  = (float)(*pw);

    // d_out is poisoned 0xAA each call: zero all 500 outputs up front.
    for (int j = lane; j < 4 * MAX_OUT + MAX_OUT; j += 64) out[j] = 0.0f;
    for (int j = lane; j < n_groups; j += 64) {
        g_s[j] = ggs[j]; g_i[j] = ggi[j]; g_b[j] = ggbox[j];
    }
    __syncthreads();

    // build supergroup maxima (scan order = index order => first-occurrence ties)
    if (lane < n_sg) {
        float bs = -3.0f; int bg = -1;
        int base = lane << 6;
        int end  = base + 64; if (end > n_groups) end = n_groups;
        for (int j = base; j < end; ++j) {
            float v = g_s[j];
            if (v > bs) { bs = v; bg = j; }   // strict > keeps first occurrence
        }
        sg_s[lane] = bs; sg_g[lane] = bg;
    }
    __syncthreads();

    int kept = 0;
    for (;;) {
        if (kept >= MAX_OUT) break;
        // ---- level-2 argmax over supergroups (one lane each) ----
        float vs = (lane < n_sg) ? sg_s[lane] : -4.0f;
        int   vg = (lane < n_sg) ? sg_g[lane] : 0x7fffffff;
        #pragma unroll
        for (int off = 32; off > 0; off >>= 1) {
            float os = __shfl_down(vs, off);
            int   og = __shfl_down(vg, off);
            if (os > vs || (os == vs && og < vg)) { vs = os; vg = og; }
        }
        vs = __shfl(vs, 0); vg = __shfl(vg, 0);
        if (vs <= 0.0f) break;                 // all candidates exhausted

        const int    g     = vg;
        const int    idx   = g_i[g];
        const float  score = vs;
        const float4 bb    = g_b[g];
        const float y1 = bb.x, x1 = bb.y, y2 = bb.z, x2 = bb.w;
        const float area_c = (y2 - y1) * (x2 - x1);

        // ---- lazy rejection: IoU vs previously-kept boxes (<=100) ----
        bool rej = false;
        for (int base = 0; base < kept; base += 64) {
            int k = base + lane;
            bool hit = false;
            if (k < kept) {
                float yy1 = fmaxf(y1, kb_y1[k]);
                float xx1 = fmaxf(x1, kb_x1[k]);
                float yy2 = fminf(y2, kb_y2[k]);
                float xx2 = fminf(x2, kb_x2[k]);
                float inter = fmaxf(yy2 - yy1, 0.0f) * fmaxf(xx2 - xx1, 0.0f);
                float iou = inter / (area_c + kb_a[k] - inter + 1e-9f);
                hit = iou > NMS_THR;
            }
            if (__any(hit)) { rej = true; break; }
        }

        // ---- rescan popped group: issue loads FIRST, then fire suppression ----
        {
            int i2 = (g << 6) + lane;
            float  s2 = -2.0f; int bi2 = i2;
            float4 b2 = make_float4(0.f, 0.f, 0.f, 0.f);
            if (i2 < N) {
                s2 = active[i2];               // load issued before the store below
                b2 = boxes[i2];                // coalesced 1KB, L2/L3-warm
            }
            if (lane == (idx & 63) && i2 == idx) s2 = -1.0f;  // mask current pop
            if (lane == 0) active[idx] = -1.0f;               // history for later pops
            #pragma unroll
            for (int off = 32; off > 0; off >>= 1) {
                float os = __shfl_down(s2, off);
                int   oi = __shfl_down(bi2, off);
                if (os > s2 || (os == s2 && oi < bi2)) { s2 = os; bi2 = oi; }
            }
            int w2 = __shfl(bi2, 0) & 63;
            float ny1 = __shfl(b2.x, w2);
            float nx1 = __shfl(b2.y, w2);
            float ny2 = __shfl(b2.z, w2);
            float nx2 = __shfl(b2.w, w2);
            if (lane == 0) {
                g_s[g] = s2; g_i[g] = bi2;
                g_b[g] = make_float4(ny1, nx1, ny2, nx2);
            }
        }
        __syncthreads();
        // ---- rescan popped supergroup ----
        {
            int sg = g >> 6;
            int gj = (sg << 6) + lane;
            float s3 = (gj < n_groups) ? g_s[gj] : -4.0f;
            int   g3 = (gj < n_groups) ? gj : 0x7fffffff;
            #pragma unroll
            for (int off = 32; off > 0; off >>= 1) {
                float os = __shfl_down(s3, off);
                int   og = __shfl_down(g3, off);
                if (os > s3 || (os == s3 && og < g3)) { s3 = os; g3 = og; }
            }
            if (lane == 0) { sg_s[sg] = s3; sg_g[sg] = g3; }
        }
        __syncthreads();

        if (!rej) {
            if (lane == 0) {
                kb_y1[kept] = y1; kb_x1[kept] = x1;
                kb_y2[kept] = y2; kb_x2[kept] = x2; kb_a[kept] = area_c;
                // size filter only zeroes OUTPUT; the box still suppresses.
                float h = y2 - y1, w = x2 - x1;
                if (h > MIN_SZ && w > MIN_SZ) {
                    out[4 * kept + 0] = y1 / img_h;
                    out[4 * kept + 1] = x1 / img_w;
                    out[4 * kept + 2] = y2 / img_h;
                    out[4 * MAX_OUT + kept] = score;
                    out[4 * kept + 3] = x2 / img_w;
                }
            }
            __syncthreads();   // kb_* visible before next iteration's IoU reads
            kept++;
        }
    }
}

extern "C" void kernel_launch(void* const* d_in, const int* in_sizes, int n_in,
                              void* d_out, int out_size, void* d_ws, size_t ws_size,
                              hipStream_t stream) {
    const float* proposals = (const float*)d_in[0];   // [N,4] yxyx pixels
    const float* cls       = (const float*)d_in[1];   // [N,2] logits
    const int*   ph        = (const int*)d_in[2];     // image_h (scalar)
    const int*   pw        = (const int*)d_in[3];     // image_w (scalar)
    float*       out       = (float*)d_out;           // 400 boxes + 100 cls

    int N = in_sizes[0] / 4;
    if (N > N_CAP) N = N_CAP;   // fixed-shape problem; defensive clamp

    // workspace layout (16B-aligned first): gbox[G_CAP] f4 | active[N] | gs | gi
    char*   ws     = (char*)d_ws;
    float4* gbox   = (float4*)ws;
    float*  active = (float*)(ws + (size_t)G_CAP * 16);
    float*  gs     = (float*)(ws + (size_t)G_CAP * 16 + (size_t)N_CAP * 4);
    int*    gi     = (int*)  (ws + (size_t)G_CAP * 16 + (size_t)N_CAP * 4 + (size_t)G_CAP * 4);

    int blocks = (N + 255) / 256;
    score_groups_kernel<<<blocks, 256, 0, stream>>>(
        (const float4*)proposals, (const float2*)cls, active, gs, gi, gbox, N);
    nms_kernel<<<1, 64, 0, stream>>>(
        (const float4*)proposals, active, gs, gi, gbox, ph, pw, out, N);
}

// Round 4
// 296.643 us; speedup vs baseline: 1.0669x; 1.0669x over previous
//
#include <hip/hip_runtime.h>

// RPN proposal selector: softmax-score -> threshold -> greedy NMS (top-100)
// -> small-box filter -> scale to fraction-of-image.
//
// Structural insight: the reference's greedy NMS pops candidates in
// descending (score, idx-asc) order, and every pop is a KEEP (suppressed
// boxes are never popped; a pop only removes itself). So greedy-NMS ==
// walk candidates in sorted order, keep iff IoU<=thr vs all previously-kept.
// The sorted order is STATIC and can be materialized in parallel:
//   A) zero histogram
//   B) softmax -> p_bits per box (0 if p<=0.7) + atomic histogram over
//      512-ulp bins of the score's float bits (monotone with score)
//   C) single block: suffix-sum histogram -> bin threshold covering top ~160
//      candidates -> compact (p_bits,~idx) u64 keys -> bitonic sort ->
//      serial IoU walk (wave 0, kept list in registers, next-candidate
//      prefetch). Batching loop lowers the threshold if more candidates
//      are needed (exact fallback).
//
// Numerics validated on HW (round 2): expf softmax == JAX softmax bit-exact
// (absmax 0.0), so bit-order == score-order is exact.

#define CLS_THR 0.7f
#define NMS_THR 0.7f
#define MAX_OUT 100
#define MIN_SZ  3.0f

#define N_CAP     147456
#define BASE_BITS 0x3F333334u   // bit pattern just above 0.7f (all p>0.7 are >= this)
#define BIN_SHIFT 9             // 512 ulps per bin
#define NBINS     9831          // ((0x3F800000 - BASE_BITS) >> 9) + 1; bin(1.0f)=9830
#define NCHUNK    615           // ceil(NBINS/16)
#define CHUNK_PAD 1024
#define TARGET    160u          // candidates per batch (~110 typically examined)
#define CAP       4096          // LDS key buffer (batch = TARGET + one bin's ties)
#define PFCAP     1024          // boxes prefetched to LDS

__global__ void zero_hist_kernel(unsigned int* __restrict__ hist) {
    int i = blockIdx.x * blockDim.x + threadIdx.x;
    if (i < NBINS) hist[i] = 0u;
}

__global__ void score_kernel(const float2* __restrict__ cls,
                             unsigned int* __restrict__ pbits,
                             unsigned int* __restrict__ hist, int N) {
    int i = blockIdx.x * blockDim.x + threadIdx.x;
    if (i >= N) return;
    float2 l = cls[i];
    // match jax.nn.softmax numerics exactly: exp(x - max) / sum
    float m  = fmaxf(l.x, l.y);
    float e0 = expf(l.x - m);
    float e1 = expf(l.y - m);
    float p  = e0 / (e0 + e1);
    unsigned int b = 0u;
    if (p > CLS_THR) {
        b = __float_as_uint(p);             // positive floats: bit order == value order
        atomicAdd(&hist[(b - BASE_BITS) >> BIN_SHIFT], 1u);
    }
    pbits[i] = b;
}

__launch_bounds__(256)
__global__ void select_kernel(const float4* __restrict__ boxes,
                              const unsigned int* __restrict__ pbits,
                              const unsigned int* __restrict__ hist,
                              const int* __restrict__ ph, const int* __restrict__ pw,
                              float* __restrict__ out, int N)
{
    __shared__ unsigned int s_chunk[CHUNK_PAD];      // 16-bin chunk sums -> suffix sums
    __shared__ unsigned long long s_kbuf[CAP];       // sorted candidate keys (32 KB)
    __shared__ float4 s_bbox[PFCAP];                 // prefetched candidate boxes (16 KB)
    __shared__ float s_klist[MAX_OUT][5];            // kept: y1,x1,y2,x2,score
    __shared__ unsigned long long s_sel;
    __shared__ unsigned int s_cnt;
    __shared__ int s_kept;

    const int tid  = threadIdx.x;
    const int lane = tid & 63;
    const int wave = tid >> 6;
    const float img_h = (float)(*ph);
    const float img_w = (float)(*pw);

    // ---- 1. chunk sums of the histogram (16 bins/chunk) ----
    for (int c = tid; c < CHUNK_PAD; c += 256) {
        unsigned int s = 0u;
        int b0 = c * 16;
        if (b0 < NBINS) {
            int b1 = b0 + 16; if (b1 > NBINS) b1 = NBINS;
            for (int b = b0; b < b1; ++b) s += hist[b];
        }
        s_chunk[c] = s;
    }
    __syncthreads();
    // ---- 2. suffix sums over chunks (Hillis-Steele, read / barrier / write) ----
    for (int st = 1; st < CHUNK_PAD; st <<= 1) {
        int c0 = tid, c1 = tid + 256, c2 = tid + 512, c3 = tid + 768;
        unsigned int a0 = (c0 + st < CHUNK_PAD) ? s_chunk[c0 + st] : 0u;
        unsigned int a1 = (c1 + st < CHUNK_PAD) ? s_chunk[c1 + st] : 0u;
        unsigned int a2 = (c2 + st < CHUNK_PAD) ? s_chunk[c2 + st] : 0u;
        unsigned int a3 = (c3 + st < CHUNK_PAD) ? s_chunk[c3 + st] : 0u;
        __syncthreads();
        s_chunk[c0] += a0; s_chunk[c1] += a1; s_chunk[c2] += a2; s_chunk[c3] += a3;
        __syncthreads();
    }

    // per-thread kept-box register slots (only wave 0's are used)
    float k0y1=0.f,k0x1=0.f,k0y2=0.f,k0x2=0.f,k0a=0.f;
    float k1y1=0.f,k1x1=0.f,k1y2=0.f,k1x2=0.f,k1a=0.f;
    int kept = 0;
    unsigned int consumed = 0u;
    int hi = NBINS;                       // exclusive high-watermark bin
    bool done = false;

    while (!done) {
        // ---- 3. cutoff bin c = max bin with suffix(bin)-consumed >= TARGET ----
        if (tid == 0) { s_sel = 0ull; s_cnt = 0u; }
        __syncthreads();
        for (int c = tid; c < NCHUNK; c += 256) {
            unsigned int s = (c + 1 < CHUNK_PAD) ? s_chunk[c + 1] : 0u;
            int b0 = c * 16;
            int b1 = b0 + 16; if (b1 > NBINS) b1 = NBINS;
            unsigned long long best = 0ull;
            for (int b = b1 - 1; b >= b0; --b) {   // downward: first hit = max bin in chunk
                s += hist[b];
                if (s > consumed) {
                    unsigned int avail = s - consumed;
                    if (avail >= TARGET) { best = ((unsigned long long)b << 32) | avail; break; }
                }
            }
            if (best) atomicMax(&s_sel, best);
        }
        __syncthreads();
        unsigned long long sel = s_sel;
        int cbin; unsigned int M;
        if (sel) { cbin = (int)(sel >> 32); M = (unsigned int)sel; }
        else {
            cbin = 0;
            unsigned int total = s_chunk[0];
            M = (total > consumed) ? (total - consumed) : 0u;
        }
        if (M == 0u) break;                        // nothing left at all
        unsigned int M_eff = (M > CAP) ? CAP : M;  // clamp (unreachable with 512-ulp bins)
        unsigned int th_lo = BASE_BITS + ((unsigned int)cbin << BIN_SHIFT);
        unsigned int th_hi = BASE_BITS + ((unsigned int)hi   << BIN_SHIFT); // hi=NBINS covers p=1.0

        // ---- 4. compact batch candidates into LDS key buffer ----
        for (int i = tid; i < N; i += 256) {
            unsigned int pb = pbits[i];
            if (pb >= th_lo && pb < th_hi) {
                unsigned int slot = atomicAdd(&s_cnt, 1u);
                if (slot < CAP)
                    s_kbuf[slot] = ((unsigned long long)pb << 32) | (unsigned int)(~i);
            }
        }
        __syncthreads();
        // pad to pow2 for bitonic (pad key 0 sorts to the end in descending order)
        unsigned int Mpad = 1u; while (Mpad < M_eff) Mpad <<= 1;
        for (unsigned int i = M_eff + tid; i < Mpad; i += 256) s_kbuf[i] = 0ull;
        __syncthreads();

        // ---- 5. bitonic sort, DESCENDING by (score_bits, ~idx) ----
        for (unsigned int k = 2; k <= Mpad; k <<= 1) {
            for (unsigned int j = k >> 1; j > 0; j >>= 1) {
                for (unsigned int i = tid; i < Mpad; i += 256) {
                    unsigned int ixj = i ^ j;
                    if (ixj > i) {
                        unsigned long long a = s_kbuf[i], b = s_kbuf[ixj];
                        bool dir = ((i & k) == 0u);          // descending overall
                        if ((a < b) == dir) { s_kbuf[i] = b; s_kbuf[ixj] = a; }
                    }
                }
                __syncthreads();
            }
        }

        // ---- 6. prefetch candidate boxes (sorted order) into LDS ----
        unsigned int PF = (M_eff < PFCAP) ? M_eff : PFCAP;
        for (unsigned int t = tid; t < PF; t += 256) {
            int idx = (int)(~(unsigned int)s_kbuf[t]);
            s_bbox[t] = boxes[idx];
        }
        __syncthreads();

        // ---- 7. serial IoU walk (wave 0; kept list in registers; next-candidate
        //         prefetch hides the LDS/global load latency) ----
        if (wave == 0) {
            int w = 0;
            unsigned long long key = s_kbuf[0];
            float4 cb = s_bbox[0];                         // PF >= 1 when M_eff >= 1
            while (kept < MAX_OUT && w < (int)M_eff) {
                // prefetch next candidate (independent of this iteration's outcome)
                int wn = w + 1;
                unsigned long long nkey = 0ull;
                float4 ncb = cb;
                if (wn < (int)M_eff) {
                    nkey = s_kbuf[wn];
                    ncb = (wn < (int)PF) ? s_bbox[wn]
                                         : boxes[(int)(~(unsigned int)nkey)];
                }
                // process current candidate
                float sc  = __uint_as_float((unsigned int)(key >> 32));
                float cy1 = cb.x, cx1 = cb.y, cy2 = cb.z, cx2 = cb.w;
                float ca  = (cy2 - cy1) * (cx2 - cx1);
                bool hit = false;
                if (lane < kept) {
                    float yy1 = fmaxf(cy1, k0y1), xx1 = fmaxf(cx1, k0x1);
                    float yy2 = fminf(cy2, k0y2), xx2 = fminf(cx2, k0x2);
                    float inter = fmaxf(yy2 - yy1, 0.0f) * fmaxf(xx2 - xx1, 0.0f);
                    float iou = inter / (ca + k0a - inter + 1e-9f);  // exact ref expr
                    hit = iou > NMS_THR;
                }
                if (lane + 64 < kept) {
                    float yy1 = fmaxf(cy1, k1y1), xx1 = fmaxf(cx1, k1x1);
                    float yy2 = fminf(cy2, k1y2), xx2 = fminf(cx2, k1x2);
                    float inter = fmaxf(yy2 - yy1, 0.0f) * fmaxf(xx2 - xx1, 0.0f);
                    float iou = inter / (ca + k1a - inter + 1e-9f);
                    hit = hit || (iou > NMS_THR);
                }
                if (!__any(hit)) {
                    if (kept < 64) {
                        if (lane == kept) { k0y1=cy1; k0x1=cx1; k0y2=cy2; k0x2=cx2; k0a=ca; }
                    } else {
                        if (lane == kept - 64) { k1y1=cy1; k1x1=cx1; k1y2=cy2; k1x2=cx2; k1a=ca; }
                    }
                    if (lane == 0) {
                        s_klist[kept][0]=cy1; s_klist[kept][1]=cx1;
                        s_klist[kept][2]=cy2; s_klist[kept][3]=cx2;
                        s_klist[kept][4]=sc;
                    }
                    kept++;
                }
                key = nkey; cb = ncb; w = wn;
            }
            if (tid == 0) s_kept = kept;
        }
        __syncthreads();
        kept = s_kept;                              // broadcast to all waves

        consumed += M;                              // whole bin-range consumed
        hi = cbin;
        if (kept >= MAX_OUT || cbin == 0) done = true;
    }

    __syncthreads();
    // ---- 8. write all 500 outputs (d_out is poisoned each call) ----
    for (int j = tid; j < 4 * MAX_OUT + MAX_OUT; j += 256) {
        float val = 0.0f;
        if (j < 4 * MAX_OUT) {
            int k = j >> 2, cc = j & 3;
            if (k < kept) {
                float h = s_klist[k][2] - s_klist[k][0];
                float w = s_klist[k][3] - s_klist[k][1];
                if (h > MIN_SZ && w > MIN_SZ) {
                    float scale = (cc == 0 || cc == 2) ? img_h : img_w;
                    val = s_klist[k][cc] / scale;
                }
            }
        } else {
            int k = j - 4 * MAX_OUT;
            if (k < kept) {
                float h = s_klist[k][2] - s_klist[k][0];
                float w = s_klist[k][3] - s_klist[k][1];
                if (h > MIN_SZ && w > MIN_SZ) val = s_klist[k][4];
            }
        }
        out[j] = val;
    }
}

extern "C" void kernel_launch(void* const* d_in, const int* in_sizes, int n_in,
                              void* d_out, int out_size, void* d_ws, size_t ws_size,
                              hipStream_t stream) {
    const float* proposals = (const float*)d_in[0];   // [N,4] yxyx pixels
    const float* cls       = (const float*)d_in[1];   // [N,2] logits
    const int*   ph        = (const int*)d_in[2];     // image_h (scalar)
    const int*   pw        = (const int*)d_in[3];     // image_w (scalar)
    float*       out       = (float*)d_out;           // 400 boxes + 100 scores

    int N = in_sizes[0] / 4;
    if (N > N_CAP) N = N_CAP;   // fixed-shape problem; defensive clamp

    // workspace: pbits[N_CAP] u32 | hist[NBINS] u32
    char* ws = (char*)d_ws;
    unsigned int* pbits = (unsigned int*)ws;
    unsigned int* hist  = (unsigned int*)(ws + (size_t)N_CAP * 4);

    zero_hist_kernel<<<(NBINS + 255) / 256, 256, 0, stream>>>(hist);
    score_kernel<<<(N + 255) / 256, 256, 0, stream>>>((const float2*)cls, pbits, hist, N);
    select_kernel<<<1, 256, 0, stream>>>((const float4*)proposals, pbits, hist,
                                         ph, pw, out, N);
}

// Round 5
// 172.794 us; speedup vs baseline: 1.8317x; 1.7167x over previous
//
#include <hip/hip_runtime.h>

// RPN proposal selector: softmax-score -> threshold -> greedy NMS (top-100)
// -> small-box filter -> scale to fraction-of-image.
//
// Greedy-NMS == walk candidates in descending (score, idx-asc) order, keep
// iff IoU<=thr vs all previously-kept (pop order is static). Pipeline:
//   A) zero histogram (padded to 16384 bins so sums need no bounds checks)
//   B) softmax -> p_bits per box (0 if p<=0.7) + atomic histogram over
//      512-ulp bins of the score's float bits (monotone with score)
//   C) single block: suffix-sum histogram -> bin threshold covering top ~160
//      candidates -> compact (p_bits,~idx) u64 keys -> bitonic sort ->
//      serial IoU walk (wave 0, kept list in registers, next-candidate
//      prefetch). Batching loop lowers threshold if more needed (exact).
//
// ROUND-4 LESSON (measured): the compaction/hist scans ran 1 load per
// iteration -> 576 serial L3-latency rounds = 230 us even fully cached.
// Fix: explicit register-strip loads (32 independent loads in flight, one
// vmcnt wait per strip) -> 18 latency rounds. Hand-made MLP, since the
// compiler won't pipeline loops containing atomics/control flow.
//
// Numerics validated on HW (round 2/4): expf softmax == JAX softmax
// bit-exact (absmax 0.0), so bit-order == score-order is exact.

#define CLS_THR 0.7f
#define NMS_THR 0.7f
#define MAX_OUT 100
#define MIN_SZ  3.0f

#define N_CAP     147456
#define BASE_BITS 0x3F333334u   // bit pattern just above 0.7f
#define BIN_SHIFT 9             // 512 ulps per bin
#define NBINS     9831          // ((0x3F800000 - BASE_BITS) >> 9) + 1
#define NCHUNK    615           // ceil(NBINS/16)
#define CHUNK_PAD 1024
#define HIST_PAD  (CHUNK_PAD * 16)   // 16384 bins allocated/zeroed (pad reads 0)
#define TARGET    160u          // candidates per batch (~110 typically examined)
#define CAP       4096          // LDS key buffer
#define PFCAP     1024          // boxes prefetched to LDS
#define STRIP     32            // loads in flight per compaction round

__global__ void zero_hist_kernel(unsigned int* __restrict__ hist) {
    int i = blockIdx.x * blockDim.x + threadIdx.x;
    if (i < HIST_PAD) hist[i] = 0u;
}

__global__ void score_kernel(const float2* __restrict__ cls,
                             unsigned int* __restrict__ pbits,
                             unsigned int* __restrict__ hist, int N) {
    int i = blockIdx.x * blockDim.x + threadIdx.x;
    if (i >= N) return;
    float2 l = cls[i];
    // match jax.nn.softmax numerics exactly: exp(x - max) / sum
    float m  = fmaxf(l.x, l.y);
    float e0 = expf(l.x - m);
    float e1 = expf(l.y - m);
    float p  = e0 / (e0 + e1);
    unsigned int b = 0u;
    if (p > CLS_THR) {
        b = __float_as_uint(p);             // positive floats: bit order == value order
        atomicAdd(&hist[(b - BASE_BITS) >> BIN_SHIFT], 1u);
    }
    pbits[i] = b;
}

__launch_bounds__(256)
__global__ void select_kernel(const float4* __restrict__ boxes,
                              const unsigned int* __restrict__ pbits,
                              const unsigned int* __restrict__ hist,
                              const int* __restrict__ ph, const int* __restrict__ pw,
                              float* __restrict__ out, int N)
{
    __shared__ unsigned int s_chunk[CHUNK_PAD];      // 16-bin chunk sums -> suffix sums
    __shared__ unsigned long long s_kbuf[CAP];       // sorted candidate keys (32 KB)
    __shared__ float4 s_bbox[PFCAP];                 // prefetched candidate boxes (16 KB)
    __shared__ float s_klist[MAX_OUT][5];            // kept: y1,x1,y2,x2,score
    __shared__ unsigned long long s_sel;
    __shared__ unsigned int s_cnt;
    __shared__ int s_kept;

    const int tid  = threadIdx.x;
    const int lane = tid & 63;
    const int wave = tid >> 6;
    const float img_h = (float)(*ph);
    const float img_w = (float)(*pw);

    // ---- 1. chunk sums of the histogram (16 unconditional loads in flight) ----
    for (int c = tid; c < CHUNK_PAD; c += 256) {
        unsigned int h[16];
        #pragma unroll
        for (int u = 0; u < 16; ++u) h[u] = hist[c * 16 + u];   // pad bins read 0
        unsigned int s = 0u;
        #pragma unroll
        for (int u = 0; u < 16; ++u) s += h[u];
        s_chunk[c] = s;
    }
    __syncthreads();
    // ---- 2. suffix sums over chunks (Hillis-Steele, read / barrier / write) ----
    for (int st = 1; st < CHUNK_PAD; st <<= 1) {
        int c0 = tid, c1 = tid + 256, c2 = tid + 512, c3 = tid + 768;
        unsigned int a0 = (c0 + st < CHUNK_PAD) ? s_chunk[c0 + st] : 0u;
        unsigned int a1 = (c1 + st < CHUNK_PAD) ? s_chunk[c1 + st] : 0u;
        unsigned int a2 = (c2 + st < CHUNK_PAD) ? s_chunk[c2 + st] : 0u;
        unsigned int a3 = (c3 + st < CHUNK_PAD) ? s_chunk[c3 + st] : 0u;
        __syncthreads();
        s_chunk[c0] += a0; s_chunk[c1] += a1; s_chunk[c2] += a2; s_chunk[c3] += a3;
        __syncthreads();
    }

    // per-thread kept-box register slots (only wave 0's are used)
    float k0y1=0.f,k0x1=0.f,k0y2=0.f,k0x2=0.f,k0a=0.f;
    float k1y1=0.f,k1x1=0.f,k1y2=0.f,k1x2=0.f,k1a=0.f;
    int kept = 0;
    unsigned int consumed = 0u;
    int hi = NBINS;                       // exclusive high-watermark bin
    bool done = false;

    while (!done) {
        // ---- 3. cutoff bin = max bin with suffix(bin)-consumed >= TARGET ----
        if (tid == 0) { s_sel = 0ull; s_cnt = 0u; }
        __syncthreads();
        for (int c = tid; c < NCHUNK; c += 256) {
            unsigned int h[16];
            #pragma unroll
            for (int u = 0; u < 16; ++u) h[u] = hist[c * 16 + u];
            unsigned int s = s_chunk[c + 1];           // c+1 <= NCHUNK < CHUNK_PAD
            unsigned long long best = 0ull;
            #pragma unroll
            for (int u = 15; u >= 0; --u) {            // downward: first hit = max bin
                s += h[u];
                if (!best && s > consumed) {
                    unsigned int avail = s - consumed;
                    if (avail >= TARGET)
                        best = ((unsigned long long)(c * 16 + u) << 32) | avail;
                }
            }
            if (best) atomicMax(&s_sel, best);
        }
        __syncthreads();
        unsigned long long sel = s_sel;
        int cbin; unsigned int M;
        if (sel) { cbin = (int)(sel >> 32); M = (unsigned int)sel; }
        else {
            cbin = 0;
            unsigned int total = s_chunk[0];
            M = (total > consumed) ? (total - consumed) : 0u;
        }
        if (M == 0u) break;                        // nothing left at all
        unsigned int M_eff = (M > CAP) ? CAP : M;  // clamp (unreachable for this data)
        unsigned int th_lo = BASE_BITS + ((unsigned int)cbin << BIN_SHIFT);
        unsigned int th_hi = BASE_BITS + ((unsigned int)hi   << BIN_SHIFT);

        // ---- 4. compact candidates: STRIP independent loads per round ----
        for (int base = 0; base < N; base += 256 * STRIP) {
            unsigned int v[STRIP];
            #pragma unroll
            for (int u = 0; u < STRIP; ++u) {
                int i = base + u * 256 + tid;
                v[u] = (i < N) ? pbits[i] : 0u;        // N==147456: never OOB, kept safe
            }
            #pragma unroll
            for (int u = 0; u < STRIP; ++u) {
                unsigned int pb = v[u];
                if (pb >= th_lo && pb < th_hi) {
                    int i = base + u * 256 + tid;
                    unsigned int slot = atomicAdd(&s_cnt, 1u);
                    if (slot < CAP)
                        s_kbuf[slot] = ((unsigned long long)pb << 32) | (unsigned int)(~i);
                }
            }
        }
        __syncthreads();
        // pad to pow2 for bitonic (pad key 0 sorts to the end in descending order)
        unsigned int Mpad = 1u; while (Mpad < M_eff) Mpad <<= 1;
        for (unsigned int i = M_eff + tid; i < Mpad; i += 256) s_kbuf[i] = 0ull;
        __syncthreads();

        // ---- 5. bitonic sort, DESCENDING by (score_bits, ~idx) ----
        for (unsigned int k = 2; k <= Mpad; k <<= 1) {
            for (unsigned int j = k >> 1; j > 0; j >>= 1) {
                for (unsigned int i = tid; i < Mpad; i += 256) {
                    unsigned int ixj = i ^ j;
                    if (ixj > i) {
                        unsigned long long a = s_kbuf[i], b = s_kbuf[ixj];
                        bool dir = ((i & k) == 0u);          // descending overall
                        if ((a < b) == dir) { s_kbuf[i] = b; s_kbuf[ixj] = a; }
                    }
                }
                __syncthreads();
            }
        }

        // ---- 6. prefetch candidate boxes (sorted order) into LDS ----
        unsigned int PF = (M_eff < PFCAP) ? M_eff : PFCAP;
        for (unsigned int t = tid; t < PF; t += 256) {
            int idx = (int)(~(unsigned int)s_kbuf[t]);
            s_bbox[t] = boxes[idx];
        }
        __syncthreads();

        // ---- 7. serial IoU walk (wave 0; kept in registers; 1-deep prefetch) ----
        if (wave == 0) {
            int w = 0;
            unsigned long long key = s_kbuf[0];
            float4 cb = s_bbox[0];
            while (kept < MAX_OUT && w < (int)M_eff) {
                int wn = w + 1;
                unsigned long long nkey = 0ull;
                float4 ncb = cb;
                if (wn < (int)M_eff) {
                    nkey = s_kbuf[wn];
                    ncb = (wn < (int)PF) ? s_bbox[wn]
                                         : boxes[(int)(~(unsigned int)nkey)];
                }
                float sc  = __uint_as_float((unsigned int)(key >> 32));
                float cy1 = cb.x, cx1 = cb.y, cy2 = cb.z, cx2 = cb.w;
                float ca  = (cy2 - cy1) * (cx2 - cx1);
                bool hit = false;
                if (lane < kept) {
                    float yy1 = fmaxf(cy1, k0y1), xx1 = fmaxf(cx1, k0x1);
                    float yy2 = fminf(cy2, k0y2), xx2 = fminf(cx2, k0x2);
                    float inter = fmaxf(yy2 - yy1, 0.0f) * fmaxf(xx2 - xx1, 0.0f);
                    float iou = inter / (ca + k0a - inter + 1e-9f);  // exact ref expr
                    hit = iou > NMS_THR;
                }
                if (lane + 64 < kept) {
                    float yy1 = fmaxf(cy1, k1y1), xx1 = fmaxf(cx1, k1x1);
                    float yy2 = fminf(cy2, k1y2), xx2 = fminf(cx2, k1x2);
                    float inter = fmaxf(yy2 - yy1, 0.0f) * fmaxf(xx2 - xx1, 0.0f);
                    float iou = inter / (ca + k1a - inter + 1e-9f);
                    hit = hit || (iou > NMS_THR);
                }
                if (!__any(hit)) {
                    if (kept < 64) {
                        if (lane == kept) { k0y1=cy1; k0x1=cx1; k0y2=cy2; k0x2=cx2; k0a=ca; }
                    } else {
                        if (lane == kept - 64) { k1y1=cy1; k1x1=cx1; k1y2=cy2; k1x2=cx2; k1a=ca; }
                    }
                    if (lane == 0) {
                        s_klist[kept][0]=cy1; s_klist[kept][1]=cx1;
                        s_klist[kept][2]=cy2; s_klist[kept][3]=cx2;
                        s_klist[kept][4]=sc;
                    }
                    kept++;
                }
                key = nkey; cb = ncb; w = wn;
            }
            if (tid == 0) s_kept = kept;
        }
        __syncthreads();
        kept = s_kept;                              // broadcast to all waves

        consumed += M;                              // whole bin-range consumed
        hi = cbin;
        if (kept >= MAX_OUT || cbin == 0) done = true;
    }

    __syncthreads();
    // ---- 8. write all 500 outputs (d_out is poisoned each call) ----
    for (int j = tid; j < 4 * MAX_OUT + MAX_OUT; j += 256) {
        float val = 0.0f;
        if (j < 4 * MAX_OUT) {
            int k = j >> 2, cc = j & 3;
            if (k < kept) {
                float h = s_klist[k][2] - s_klist[k][0];
                float w = s_klist[k][3] - s_klist[k][1];
                if (h > MIN_SZ && w > MIN_SZ) {
                    float scale = (cc == 0 || cc == 2) ? img_h : img_w;
                    val = s_klist[k][cc] / scale;
                }
            }
        } else {
            int k = j - 4 * MAX_OUT;
            if (k < kept) {
                float h = s_klist[k][2] - s_klist[k][0];
                float w = s_klist[k][3] - s_klist[k][1];
                if (h > MIN_SZ && w > MIN_SZ) val = s_klist[k][4];
            }
        }
        out[j] = val;
    }
}

extern "C" void kernel_launch(void* const* d_in, const int* in_sizes, int n_in,
                              void* d_out, int out_size, void* d_ws, size_t ws_size,
                              hipStream_t stream) {
    const float* proposals = (const float*)d_in[0];   // [N,4] yxyx pixels
    const float* cls       = (const float*)d_in[1];   // [N,2] logits
    const int*   ph        = (const int*)d_in[2];     // image_h (scalar)
    const int*   pw        = (const int*)d_in[3];     // image_w (scalar)
    float*       out       = (float*)d_out;           // 400 boxes + 100 scores

    int N = in_sizes[0] / 4;
    if (N > N_CAP) N = N_CAP;   // fixed-shape problem; defensive clamp

    // workspace: pbits[N_CAP] u32 | hist[HIST_PAD] u32
    char* ws = (char*)d_ws;
    unsigned int* pbits = (unsigned int*)ws;
    unsigned int* hist  = (unsigned int*)(ws + (size_t)N_CAP * 4);

    zero_hist_kernel<<<(HIST_PAD + 255) / 256, 256, 0, stream>>>(hist);
    score_kernel<<<(N + 255) / 256, 256, 0, stream>>>((const float2*)cls, pbits, hist, N);
    select_kernel<<<1, 256, 0, stream>>>((const float4*)proposals, pbits, hist,
                                         ph, pw, out, N);
}

// Round 7
// 121.662 us; speedup vs baseline: 2.6015x; 1.4203x over previous
//
#include <hip/hip_runtime.h>

// RPN proposal selector: softmax-score -> threshold -> greedy NMS (top-100)
// -> small-box filter -> scale to fraction-of-image.
//
// Greedy-NMS == walk candidates in descending (score, idx-asc) order, keep
// iff IoU<=thr vs all previously-kept (pop order is static).
//
// Pipeline: zero hist -> score_kernel (softmax -> p_bits; atomic hist over
// 512-ulp score-bit bins; bucket-sort top-1024-bin candidates at creation)
// -> select_kernel (single block: stage top hist bins in LDS, wave-0 cutoff
// scan, parallel bucket gather, barrier-free rank sort, software-pipelined
// serial IoU walk with delayed slot update + scalar pair term).
// Exact pbits-scan fallback for bucket overflow / deep cutoff.
//
// Round-4/5 lessons (measured): single-block phases are latency-bound; give
// every loop explicit MLP (strip loads) and keep serial chains minimal.
// Numerics validated on HW: expf softmax == JAX bit-exact (absmax 0.0),
// so float-bit order == score order exactly.

#define CLS_THR 0.7f
#define NMS_THR 0.7f
#define MAX_OUT 100
#define MIN_SZ  3.0f

#define N_CAP      147456
#define BASE_BITS  0x3F333334u            // bits just above 0.7f
#define BIN_SHIFT  9                      // 512 ulps per bin
#define NBINS      9831                   // ((0x3F800000-BASE_BITS)>>9)+1
#define HIST_WORDS 10240                  // padded allocation (pad reads 0)
#define TARGET     160u                   // candidates per batch
#define CAP        1024                   // LDS key buffer
#define BUCKET_NB  1024                   // top bins bucketed (p >~ 0.969)
#define BUCKET_LO  (NBINS - BUCKET_NB)    // 8807
#define BCAP       64                     // slots per bucket (expect <= ~30)
#define TOP_STAGE  2048                   // hist bins staged in LDS
#define TOPBASE    (NBINS - TOP_STAGE)    // 7783

__global__ void zero_hist_kernel(unsigned int* __restrict__ hist) {
    int i = blockIdx.x * blockDim.x + threadIdx.x;
    if (i < HIST_WORDS) hist[i] = 0u;
}

__global__ void score_kernel(const float2* __restrict__ cls,
                             unsigned int* __restrict__ pbits,
                             unsigned int* __restrict__ hist,
                             unsigned long long* __restrict__ bucket, int N) {
    int i = blockIdx.x * blockDim.x + threadIdx.x;
    if (i >= N) return;
    float2 l = cls[i];
    // match jax.nn.softmax numerics exactly: exp(x - max) / sum
    float m  = fmaxf(l.x, l.y);
    float e0 = expf(l.x - m);
    float e1 = expf(l.y - m);
    float p  = e0 / (e0 + e1);
    unsigned int b = 0u;
    if (p > CLS_THR) {
        b = __float_as_uint(p);           // positive: bit order == value order
        int bin = (int)((b - BASE_BITS) >> BIN_SHIFT);
        unsigned int old = atomicAdd(&hist[bin], 1u);
        if (bin >= BUCKET_LO && old < BCAP)
            bucket[(size_t)(bin - BUCKET_LO) * BCAP + old] =
                ((unsigned long long)b << 32) | (unsigned int)(~i);
    }
    pbits[i] = b;                          // fallback path input
}

__launch_bounds__(256)
__global__ void select_kernel(const float4* __restrict__ boxes,
                              const unsigned int* __restrict__ pbits,
                              const unsigned int* __restrict__ hist,
                              const unsigned long long* __restrict__ bucket,
                              const int* __restrict__ ph, const int* __restrict__ pw,
                              float* __restrict__ out, int N)
{
    __shared__ unsigned int s_htop[TOP_STAGE];         // top hist bins (8 KB)
    __shared__ unsigned long long s_kbuf[CAP];         // raw batch keys (8 KB)
    __shared__ unsigned long long s_sorted[CAP];       // sorted keys (8 KB)
    __shared__ float4 s_bbox[CAP];                     // candidate boxes (16 KB)
    __shared__ float s_klist[MAX_OUT][5];              // kept y1,x1,y2,x2,score
    __shared__ int s_cbin, s_ov, s_kept;
    __shared__ unsigned int s_M, s_cnt;

    const int tid  = threadIdx.x;
    const int lane = tid & 63;
    const int wave = tid >> 6;
    const float img_h = (float)(*ph);
    const float img_w = (float)(*pw);

    // ---- stage top hist bins: 8 independent loads/thread, one wait ----
    {
        unsigned int hv[8];
        #pragma unroll
        for (int r = 0; r < 8; ++r) hv[r] = hist[TOPBASE + tid + r * 256];
        #pragma unroll
        for (int r = 0; r < 8; ++r) s_htop[tid + r * 256] = hv[r];
    }
    __syncthreads();

    // wave-0 kept-box lane slots (zero box never produces an IoU hit)
    float k0y1=0.f,k0x1=0.f,k0y2=0.f,k0x2=0.f,k0a=0.f;
    float k1y1=0.f,k1x1=0.f,k1y2=0.f,k1x2=0.f,k1a=0.f;
    int kept = 0;
    int hi = NBINS;                        // exclusive high-watermark bin
    bool done = false;

    while (!done) {
        // ---- cutoff scan: wave 0 walks bins from hi-1 downward, 64/strip ----
        if (wave == 0) {
            int pos = hi; unsigned int run = 0u; int cb = -1; unsigned int M = 0u; int ov = 0;
            while (pos > 0) {
                int b = pos - 1 - lane;                   // lane 0 = highest bin
                unsigned int h = 0u;
                if (b >= TOPBASE) h = s_htop[b - TOPBASE];
                else if (b >= 0)  h = hist[b];            // deep bins: global (rare)
                unsigned int pref = h;                    // inclusive lane prefix
                #pragma unroll
                for (int o = 1; o < 64; o <<= 1) {
                    unsigned int t = __shfl_up(pref, o);
                    if (lane >= o) pref += t;
                }
                unsigned int cum = run + pref;            // suffix-from-top count
                unsigned long long okm = __ballot(b >= 0 && cum >= TARGET);
                unsigned long long ovm = __ballot(b >= 0 && h > BCAP);
                if (okm) {
                    int first = __builtin_ctzll(okm);     // highest qualifying bin
                    cb = pos - 1 - first;
                    M  = __shfl(cum, first);
                    unsigned long long lm = (first >= 63) ? ~0ull
                                          : ((1ull << (first + 1)) - 1ull);
                    if (ovm & lm) ov = 1;
                    break;
                }
                if (ovm) ov = 1;
                run += __shfl(pref, 63);
                pos -= 64;
            }
            if (cb < 0) { cb = 0; M = run; }              // sweep everything left
            if (lane == 0) { s_cbin = cb; s_M = M; s_ov = ov; s_cnt = 0u; }
        }
        __syncthreads();
        const int cbin = s_cbin;
        const unsigned int M = s_M;
        if (M == 0u) break;
        const unsigned int M_eff = (M > CAP) ? CAP : M;
        const bool usebucket = (!s_ov) && (cbin >= BUCKET_LO);

        // ---- gather batch keys ----
        if (usebucket) {
            // 4 bins per round: wave w takes bin (top-down) base+w, lane = slot
            int nb = hi - cbin;
            for (int base = 0; base < nb; base += 4) {
                int bi = base + wave;
                if (bi < nb) {
                    int b = hi - 1 - bi;
                    unsigned int cnt = s_htop[b - TOPBASE];
                    unsigned int off = 0u;
                    for (int q = 0; q < bi; ++q)          // prefix of counts above
                        off += s_htop[hi - 1 - q - TOPBASE];
                    if (lane < (int)cnt && off + lane < CAP)
                        s_kbuf[off + lane] =
                            bucket[(size_t)(b - BUCKET_LO) * BCAP + lane];
                }
            }
        } else {
            // exact fallback: strip-scan pbits (8x uint4 = 32 values in flight)
            unsigned int th_lo = BASE_BITS + ((unsigned int)cbin << BIN_SHIFT);
            unsigned int th_hi = BASE_BITS + ((unsigned int)hi   << BIN_SHIFT);
            const uint4* p4 = (const uint4*)pbits;
            int N4 = N >> 2;
            for (int base = 0; base < N4; base += 256 * 8) {
                uint4 v[8];
                #pragma unroll
                for (int u = 0; u < 8; ++u) {
                    int i4 = base + u * 256 + tid;
                    v[u] = (i4 < N4) ? p4[i4] : make_uint4(0u, 0u, 0u, 0u);
                }
                #pragma unroll
                for (int u = 0; u < 8; ++u) {
                    int i0 = (base + u * 256 + tid) << 2;
                    unsigned int pv[4] = {v[u].x, v[u].y, v[u].z, v[u].w};
                    #pragma unroll
                    for (int kk = 0; kk < 4; ++kk) {
                        unsigned int pb = pv[kk];
                        if (pb >= th_lo && pb < th_hi) {
                            unsigned int slot = atomicAdd(&s_cnt, 1u);
                            if (slot < CAP)
                                s_kbuf[slot] = ((unsigned long long)pb << 32)
                                             | (unsigned int)(~(i0 + kk));
                        }
                    }
                }
            }
        }
        __syncthreads();

        // ---- rank sort (barrier-free; broadcast LDS reads; unique keys) ----
        for (unsigned int t = tid; t < M_eff; t += 256) {
            unsigned long long kt = s_kbuf[t];
            unsigned int rank = 0u;
            #pragma unroll 8
            for (unsigned int j = 0; j < M_eff; ++j)
                rank += (s_kbuf[j] > kt) ? 1u : 0u;
            s_sorted[rank] = kt;                     // rank < M_eff <= CAP
        }
        __syncthreads();

        // ---- gather candidate boxes (scattered, parallel) ----
        for (unsigned int t = tid; t < M_eff; t += 256) {
            int idx = (int)(~(unsigned int)s_sorted[t]);
            s_bbox[t] = boxes[idx];
        }
        __syncthreads();

        // ---- software-pipelined serial walk (wave 0) ----
        // chain per iter: ballot -> OR -> keep; IoU work is one iter ahead.
        // slot update for w is DELAYED to iter w+1; w's suppression of w+1
        // enters via the precomputed scalar pair term.
        if (wave == 0 && kept < MAX_OUT) {
            float4 bc = s_bbox[0];
            unsigned int scb = (unsigned int)(s_sorted[0] >> 32);
            float cy1=bc.x, cx1=bc.y, cy2=bc.z, cx2=bc.w;
            float ca = (cy2 - cy1) * (cx2 - cx1);
            bool pend;
            {   // pend-hit for w=0 vs full current kept set
                float yy1 = fmaxf(cy1,k0y1), xx1 = fmaxf(cx1,k0x1);
                float yy2 = fminf(cy2,k0y2), xx2 = fminf(cx2,k0x2);
                float it  = fmaxf(yy2-yy1,0.f)*fmaxf(xx2-xx1,0.f);
                pend = it / (ca + k0a - it + 1e-9f) > NMS_THR;
                yy1 = fmaxf(cy1,k1y1); xx1 = fmaxf(cx1,k1x1);
                yy2 = fminf(cy2,k1y2); xx2 = fminf(cx2,k1x2);
                it  = fmaxf(yy2-yy1,0.f)*fmaxf(xx2-xx1,0.f);
                pend = pend || (it / (ca + k1a - it + 1e-9f) > NMS_THR);
            }
            bool prev_keep = false, pair_hit = false;
            float py1=0.f,px1=0.f,py2=0.f,px2=0.f,pa=0.f;
            int w = 0;
            while (true) {
                // delayed slot update for w-1 (depends on last iter's decision)
                if (prev_keep) {
                    int slot = kept - 1;
                    if (slot < 64) { if (lane == slot)      { k0y1=py1;k0x1=px1;k0y2=py2;k0x2=px2;k0a=pa; } }
                    else           { if (lane == slot - 64) { k1y1=py1;k1x1=px1;k1y2=py2;k1x2=px2;k1a=pa; } }
                }
                // finalize w: pend covers keeps < w-1; pair term covers w-1
                bool hit = __any(pend) || (prev_keep && pair_hit);
                bool keep_w = !hit;
                if (keep_w) {
                    if (lane == 0) {
                        s_klist[kept][0]=cy1; s_klist[kept][1]=cx1;
                        s_klist[kept][2]=cy2; s_klist[kept][3]=cx2;
                        s_klist[kept][4]=__uint_as_float(scb);
                    }
                    kept++;
                }
                if (kept >= MAX_OUT) break;
                int wn = w + 1;
                if (wn >= (int)M_eff) {
                    if (keep_w) {               // flush pending update for w
                        int slot = kept - 1;
                        if (slot < 64) { if (lane == slot)      { k0y1=cy1;k0x1=cx1;k0y2=cy2;k0x2=cx2;k0a=ca; } }
                        else           { if (lane == slot - 64) { k1y1=cy1;k1x1=cx1;k1y2=cy2;k1x2=cx2;k1a=ca; } }
                    }
                    break;
                }
                float4 bn = s_bbox[wn];
                unsigned int nscb = (unsigned int)(s_sorted[wn] >> 32);
                float ny1=bn.x, nx1=bn.y, ny2=bn.z, nx2=bn.w;
                float na = (ny2 - ny1) * (nx2 - nx1);
                {   // pend for wn vs lane slots (state: keeps among 0..w-1)
                    float yy1 = fmaxf(ny1,k0y1), xx1 = fmaxf(nx1,k0x1);
                    float yy2 = fminf(ny2,k0y2), xx2 = fminf(nx2,k0x2);
                    float it  = fmaxf(yy2-yy1,0.f)*fmaxf(xx2-xx1,0.f);
                    pend = it / (na + k0a - it + 1e-9f) > NMS_THR;
                    yy1 = fmaxf(ny1,k1y1); xx1 = fmaxf(nx1,k1x1);
                    yy2 = fminf(ny2,k1y2); xx2 = fminf(nx2,k1x2);
                    it  = fmaxf(yy2-yy1,0.f)*fmaxf(xx2-xx1,0.f);
                    pend = pend || (it / (na + k1a - it + 1e-9f) > NMS_THR);
                }
                {   // pair term: wn vs w (independent of decisions)
                    float yy1 = fmaxf(ny1,cy1), xx1 = fmaxf(nx1,cx1);
                    float yy2 = fminf(ny2,cy2), xx2 = fminf(nx2,cx2);
                    float it  = fmaxf(yy2-yy1,0.f)*fmaxf(xx2-xx1,0.f);
                    pair_hit = it / (na + ca - it + 1e-9f) > NMS_THR;
                }
                prev_keep = keep_w;
                py1=cy1;px1=cx1;py2=cy2;px2=cx2;pa=ca;
                cy1=ny1;cx1=nx1;cy2=ny2;cx2=nx2;ca=na; scb=nscb;
                w = wn;
            }
            if (lane == 0) s_kept = kept;
        }
        __syncthreads();
        kept = s_kept;                        // broadcast

        done = (kept >= MAX_OUT) || (cbin == 0);
        hi = cbin;
    }

    __syncthreads();
    // ---- write all 500 outputs (d_out poisoned each call) ----
    for (int j = tid; j < 4 * MAX_OUT + MAX_OUT; j += 256) {
        float val = 0.0f;
        if (j < 4 * MAX_OUT) {
            int k = j >> 2, cc = j & 3;
            if (k < kept) {
                float h = s_klist[k][2] - s_klist[k][0];
                float w = s_klist[k][3] - s_klist[k][1];
                if (h > MIN_SZ && w > MIN_SZ) {
                    float scale = (cc == 0 || cc == 2) ? img_h : img_w;
                    val = s_klist[k][cc] / scale;
                }
            }
        } else {
            int k = j - 4 * MAX_OUT;
            if (k < kept) {
                float h = s_klist[k][2] - s_klist[k][0];
                float w = s_klist[k][3] - s_klist[k][1];
                if (h > MIN_SZ && w > MIN_SZ) val = s_klist[k][4];
            }
        }
        out[j] = val;
    }
}

extern "C" void kernel_launch(void* const* d_in, const int* in_sizes, int n_in,
                              void* d_out, int out_size, void* d_ws, size_t ws_size,
                              hipStream_t stream) {
    const float* proposals = (const float*)d_in[0];   // [N,4] yxyx pixels
    const float* cls       = (const float*)d_in[1];   // [N,2] logits
    const int*   ph        = (const int*)d_in[2];     // image_h (scalar)
    const int*   pw        = (const int*)d_in[3];     // image_w (scalar)
    float*       out       = (float*)d_out;           // 400 boxes + 100 scores

    int N = in_sizes[0] / 4;
    if (N > N_CAP) N = N_CAP;   // fixed-shape problem; defensive clamp

    // ws: bucket u64[1024*64] (512KB) | pbits u32[N_CAP] | hist u32[HIST_WORDS]
    char* ws = (char*)d_ws;
    unsigned long long* bucket = (unsigned long long*)ws;
    unsigned int* pbits = (unsigned int*)(ws + (size_t)BUCKET_NB * BCAP * 8);
    unsigned int* hist  = (unsigned int*)(ws + (size_t)BUCKET_NB * BCAP * 8
                                             + (size_t)N_CAP * 4);

    zero_hist_kernel<<<(HIST_WORDS + 255) / 256, 256, 0, stream>>>(hist);
    score_kernel<<<(N + 255) / 256, 256, 0, stream>>>(
        (const float2*)cls, pbits, hist, bucket, N);
    select_kernel<<<1, 256, 0, stream>>>(
        (const float4*)proposals, pbits, hist, bucket, ph, pw, out, N);
}

// Round 8
// 96.817 us; speedup vs baseline: 3.2690x; 1.2566x over previous
//
#include <hip/hip_runtime.h>

// RPN proposal selector: softmax-score -> threshold -> greedy NMS (top-100)
// -> small-box filter -> scale to fraction-of-image.
//
// Greedy-NMS == walk candidates in descending (score, idx-asc) order, keep
// iff IoU<=thr vs all previously-kept (pop order is static).
//
// Pipeline: zero hist -> score_kernel (softmax; atomic hist over 512-ulp
// score-bit bins; bucket-sort top-1024-bin candidates at creation) ->
// select_kernel (single block: wave-0 cutoff scan over global hist,
// parallel bucket gather, barrier-free rank sort, then PARALLEL pairwise
// suppression matrix + bitmask scan -- the serial part is bit ops only).
// Exact cls-recompute fallback for bucket overflow / deep cutoff.
//
// Measured lessons: single-WG phases run at DVFS-floor clocks (~0.5 GHz);
// every serial cycle counts. R4: give scans explicit MLP. R7: the serial
// IoU walk (~15k cy) dominated; replaced by matrix+bitscan (~4k cy).
// Numerics validated on HW: expf softmax == JAX bit-exact (absmax 0.0).

#define CLS_THR 0.7f
#define NMS_THR 0.7f
#define MAX_OUT 100
#define MIN_SZ  3.0f

#define N_CAP      147456
#define BASE_BITS  0x3F333334u            // bits just above 0.7f
#define BIN_SHIFT  9                      // 512 ulps per bin
#define NBINS      9831                   // ((0x3F800000-BASE_BITS)>>9)+1
#define HIST_WORDS 10240                  // padded allocation (pad reads 0)
#define TARGET     160u                   // candidates per batch
#define CAP        512                    // LDS key buffer
#define CHUNK      128                    // suppression-matrix chunk
#define BUCKET_NB  1024                   // top bins bucketed (p >~ 0.969)
#define BUCKET_LO  (NBINS - BUCKET_NB)    // 8807
#define BCAP       64                     // slots per bucket (expect <= ~30)

__global__ void zero_hist_kernel(unsigned int* __restrict__ hist) {
    int i = blockIdx.x * blockDim.x + threadIdx.x;
    if (i < HIST_WORDS) hist[i] = 0u;
}

__device__ __forceinline__ float softmax0(float l0, float l1) {
    // match jax.nn.softmax numerics exactly: exp(x - max) / sum
    float m  = fmaxf(l0, l1);
    float e0 = expf(l0 - m);
    float e1 = expf(l1 - m);
    return e0 / (e0 + e1);
}

__global__ void score_kernel(const float4* __restrict__ cls,   // 2 boxes/vec
                             unsigned int* __restrict__ hist,
                             unsigned long long* __restrict__ bucket, int N) {
    int t = blockIdx.x * blockDim.x + threadIdx.x;
    int i = t * 2;
    if (i >= N) return;
    float4 v = cls[t];
    float p0 = softmax0(v.x, v.y);
    float p1 = softmax0(v.z, v.w);
    if (p0 > CLS_THR) {
        unsigned int b = __float_as_uint(p0);
        int bin = (int)((b - BASE_BITS) >> BIN_SHIFT);
        unsigned int old = atomicAdd(&hist[bin], 1u);
        if (bin >= BUCKET_LO && old < BCAP)
            bucket[(size_t)(bin - BUCKET_LO) * BCAP + old] =
                ((unsigned long long)b << 32) | (unsigned int)(~i);
    }
    if (p1 > CLS_THR) {
        unsigned int b = __float_as_uint(p1);
        int bin = (int)((b - BASE_BITS) >> BIN_SHIFT);
        unsigned int old = atomicAdd(&hist[bin], 1u);
        if (bin >= BUCKET_LO && old < BCAP)
            bucket[(size_t)(bin - BUCKET_LO) * BCAP + old] =
                ((unsigned long long)b << 32) | (unsigned int)(~(i + 1));
    }
}

__launch_bounds__(256)
__global__ void select_kernel(const float4* __restrict__ boxes,
                              const float4* __restrict__ cls,
                              const unsigned int* __restrict__ hist,
                              const unsigned long long* __restrict__ bucket,
                              const int* __restrict__ ph, const int* __restrict__ pw,
                              float* __restrict__ out, int N)
{
    __shared__ unsigned long long s_kbuf[CAP];     // raw batch keys (4 KB)
    __shared__ unsigned long long s_sorted[CAP];   // sorted keys (4 KB)
    __shared__ float4 s_bbox[CAP];                 // candidate boxes (8 KB)
    __shared__ unsigned int s_sup[CHUNK][4];       // suppression rows (2 KB)
    __shared__ unsigned int s_rowflag[4];          // row-nonempty bits
    __shared__ unsigned int s_seedm[4];            // suppressed-by-kept bits
    __shared__ unsigned int s_keep[4];             // keep bits of chunk
    __shared__ unsigned int s_gpack[CAP];          // bin<<16|cnt (2 KB)
    __shared__ unsigned int s_goff[CAP];           // key offsets (2 KB)
    __shared__ float  s_klist[MAX_OUT][5];         // kept y1,x1,y2,x2,score
    __shared__ float4 s_kbox[MAX_OUT];             // kept boxes (seeding)
    __shared__ float  s_karea[MAX_OUT];
    __shared__ int s_cbin, s_ov, s_kept, s_ne;
    __shared__ unsigned int s_M, s_cnt;

    const int tid  = threadIdx.x;
    const int lane = tid & 63;
    const int wave = tid >> 6;
    const float img_h = (float)(*ph);
    const float img_w = (float)(*pw);

    int kept = 0;
    int hi = NBINS;                        // exclusive high-watermark bin
    bool done = false;

    while (!done) {
        // ---- cutoff scan: wave 0 walks bins from hi-1 down, 64/strip ----
        if (wave == 0) {
            int pos = hi; unsigned int run = 0u; int cb = -1;
            unsigned int M = 0u; int ov = 0;
            while (pos > 0) {
                int b = pos - 1 - lane;                   // lane 0 = highest
                unsigned int h = (b >= 0) ? hist[b] : 0u;
                unsigned int pref = h;                    // inclusive prefix
                #pragma unroll
                for (int o = 1; o < 64; o <<= 1) {
                    unsigned int t2 = __shfl_up(pref, o);
                    if (lane >= o) pref += t2;
                }
                unsigned int cum = run + pref;            // count from top
                unsigned long long okm = __ballot(b >= 0 && cum >= TARGET);
                unsigned long long ovm = __ballot(b >= 0 && h > BCAP);
                if (okm) {
                    int first = __builtin_ctzll(okm);     // highest qual. bin
                    cb = pos - 1 - first;
                    M  = __shfl(cum, first);
                    unsigned long long lm = (first >= 63) ? ~0ull
                                          : ((1ull << (first + 1)) - 1ull);
                    if (ovm & lm) ov = 1;
                    break;
                }
                if (ovm) ov = 1;
                run += __shfl(pref, 63);
                pos -= 64;
            }
            if (cb < 0) { cb = 0; M = run; }              // sweep the rest
            if (lane == 0) { s_cbin = cb; s_M = M; s_ov = ov;
                             s_cnt = 0u; s_ne = 0; }
        }
        __syncthreads();
        const int cbin = s_cbin;
        const unsigned int M = s_M;
        if (M == 0u) break;
        const unsigned int M_eff = (M > CAP) ? CAP : M;
        const bool usebucket = (!s_ov) && (cbin >= BUCKET_LO);

        // ---- gather batch keys ----
        if (usebucket) {
            // entries pass (wave 0): (bin,cnt,offset) of nonempty bins
            if (wave == 0) {
                int pos = hi; unsigned int run = 0u; int ne = 0;
                while (pos > cbin) {
                    int b = pos - 1 - lane;
                    unsigned int h = (b >= cbin) ? hist[b] : 0u;
                    unsigned int pref = h;
                    #pragma unroll
                    for (int o = 1; o < 64; o <<= 1) {
                        unsigned int t2 = __shfl_up(pref, o);
                        if (lane >= o) pref += t2;
                    }
                    unsigned int offv = run + pref - h;   // excl. from top
                    unsigned long long nzm = __ballot(h > 0u);
                    int slot = ne + __popcll(nzm & ((1ull << lane) - 1ull));
                    if (h > 0u && slot < CAP) {
                        s_gpack[slot] = ((unsigned int)b << 16) | h;
                        s_goff[slot]  = offv;
                    }
                    ne  += __popcll(nzm);
                    run += __shfl(pref, 63);
                    pos -= 64;
                }
                if (lane == 0) s_ne = ne;
            }
            __syncthreads();
            int ne = s_ne; if (ne > CAP) ne = CAP;
            for (int e = wave; e < ne; e += 4) {          // wave per bin
                unsigned int pk = s_gpack[e];
                int b = (int)(pk >> 16);
                unsigned int cnt = pk & 0xFFFFu;
                unsigned int off = s_goff[e];
                if (lane < (int)cnt && off + lane < CAP)
                    s_kbuf[off + lane] =
                        bucket[(size_t)(b - BUCKET_LO) * BCAP + lane];
            }
        } else {
            // exact fallback: recompute scores from cls (never hit for
            // this data; kept for correctness under any input)
            unsigned int th_lo = BASE_BITS + ((unsigned int)cbin << BIN_SHIFT);
            unsigned int th_hi = BASE_BITS + ((unsigned int)hi   << BIN_SHIFT);
            int NV = N >> 1;                              // float4 count
            for (int basei = 0; basei < NV; basei += 256 * 8) {
                float4 v[8];
                #pragma unroll
                for (int u = 0; u < 8; ++u) {
                    int i4 = basei + u * 256 + tid;
                    v[u] = (i4 < NV) ? cls[i4]
                                     : make_float4(0.f, 0.f, 0.f, 0.f);
                }
                #pragma unroll
                for (int u = 0; u < 8; ++u) {
                    int i0 = (basei + u * 256 + tid) * 2;
                    float p0 = softmax0(v[u].x, v[u].y);
                    float p1 = softmax0(v[u].z, v[u].w);
                    if (p0 > CLS_THR) {
                        unsigned int b = __float_as_uint(p0);
                        if (b >= th_lo && b < th_hi) {
                            unsigned int sl = atomicAdd(&s_cnt, 1u);
                            if (sl < CAP)
                                s_kbuf[sl] = ((unsigned long long)b << 32)
                                           | (unsigned int)(~i0);
                        }
                    }
                    if (p1 > CLS_THR) {
                        unsigned int b = __float_as_uint(p1);
                        if (b >= th_lo && b < th_hi) {
                            unsigned int sl = atomicAdd(&s_cnt, 1u);
                            if (sl < CAP)
                                s_kbuf[sl] = ((unsigned long long)b << 32)
                                           | (unsigned int)(~(i0 + 1));
                        }
                    }
                }
            }
        }
        __syncthreads();

        // ---- rank sort (barrier-free; broadcast LDS reads; unique keys) ----
        for (unsigned int t = tid; t < M_eff; t += 256) {
            unsigned long long kt = s_kbuf[t];
            unsigned int rank = 0u;
            #pragma unroll 8
            for (unsigned int j = 0; j < M_eff; ++j)
                rank += (s_kbuf[j] > kt) ? 1u : 0u;
            s_sorted[rank] = kt;
        }
        __syncthreads();

        // ---- gather candidate boxes (scattered, parallel) ----
        for (unsigned int t = tid; t < M_eff; t += 256) {
            int idx = (int)(~(unsigned int)s_sorted[t]);
            s_bbox[t] = boxes[idx];
        }
        __syncthreads();

        // ---- chunked matrix-NMS ----
        int base = 0;
        while (base < (int)M_eff && kept < MAX_OUT) {
            int C = (int)M_eff - base; if (C > CHUNK) C = CHUNK;
            if (tid < CHUNK) { s_sup[tid][0] = 0u; s_sup[tid][1] = 0u;
                               s_sup[tid][2] = 0u; s_sup[tid][3] = 0u; }
            if (tid < 4) { s_rowflag[tid] = 0u; s_seedm[tid] = 0u;
                           s_keep[tid] = 0u; }
            __syncthreads();

            // seed: suppressed-by-already-kept (only after first chunk/batch)
            if (kept > 0 && tid < C) {
                float4 cb = s_bbox[base + tid];
                float ca = (cb.z - cb.x) * (cb.w - cb.y);
                bool sup = false;
                for (int j = 0; j < kept; ++j) {
                    float4 kb = s_kbox[j];
                    float yy1 = fmaxf(cb.x, kb.x), xx1 = fmaxf(cb.y, kb.y);
                    float yy2 = fminf(cb.z, kb.z), xx2 = fminf(cb.w, kb.w);
                    float it = fmaxf(yy2 - yy1, 0.f) * fmaxf(xx2 - xx1, 0.f);
                    sup = sup ||
                        (it / (ca + s_karea[j] - it + 1e-9f) > NMS_THR);
                }
                if (sup) atomicOr(&s_seedm[tid >> 5], 1u << (tid & 31));
            }
            // pairwise suppression matrix (balanced d-loop; hits are rare)
            for (int d = 1; d < C; ++d) {
                int i = tid;
                if (i + d < C) {
                    float4 a = s_bbox[base + i];
                    float4 b2 = s_bbox[base + i + d];
                    float aa = (a.z - a.x) * (a.w - a.y);
                    float ab = (b2.z - b2.x) * (b2.w - b2.y);
                    float yy1 = fmaxf(a.x, b2.x), xx1 = fmaxf(a.y, b2.y);
                    float yy2 = fminf(a.z, b2.z), xx2 = fminf(a.w, b2.w);
                    float it = fmaxf(yy2 - yy1, 0.f) * fmaxf(xx2 - xx1, 0.f);
                    if (it / (aa + ab - it + 1e-9f) > NMS_THR) {
                        int j = i + d;
                        atomicOr(&s_sup[i][j >> 5], 1u << (j & 31));
                        atomicOr(&s_rowflag[i >> 5], 1u << (i & 31));
                    }
                }
            }
            __syncthreads();

            // bitmask scan (wave 0, uniform; serial part = bit ops only)
            if (wave == 0) {
                unsigned int m0 = s_seedm[0], m1 = s_seedm[1],
                             m2 = s_seedm[2], m3 = s_seedm[3];
                unsigned int ku[4] = {0u, 0u, 0u, 0u};
                unsigned int mg[4] = {m0, m1, m2, m3};
                int k = kept;
                #pragma unroll
                for (int g = 0; g < 4; ++g) {
                    int lo = g * 32;
                    if (lo < C && k < MAX_OUT) {
                        int cg = C - lo; if (cg > 32) cg = 32;
                        unsigned int vmask = (cg >= 32) ? 0xFFFFFFFFu
                                            : ((1u << cg) - 1u);
                        unsigned int avail = vmask & ~mg[g];
                        unsigned int hitr = s_rowflag[g] & avail;
                        if (hitr == 0u) {
                            int c2 = __popc(avail);
                            int need = MAX_OUT - k;
                            if (c2 <= need) { ku[g] |= avail; k += c2; }
                            else {
                                unsigned int kw = avail; int cc = c2;
                                while (cc > need) {
                                    kw &= ~(0x80000000u >> __builtin_clz(kw));
                                    --cc;
                                }
                                ku[g] |= kw; k = MAX_OUT;
                            }
                        } else {
                            unsigned int rem = avail;
                            while (rem && k < MAX_OUT) {
                                int b = __builtin_ctz(rem);
                                ku[g] |= (1u << b); ++k;
                                if ((s_rowflag[g] >> b) & 1u) {
                                    int i = lo + b;
                                    mg[0] |= s_sup[i][0];
                                    mg[1] |= s_sup[i][1];
                                    mg[2] |= s_sup[i][2];
                                    mg[3] |= s_sup[i][3];
                                    rem &= ~mg[g];
                                }
                                rem &= ~(1u << b);
                            }
                        }
                    }
                }
                if (lane == 0) {
                    s_keep[0] = ku[0]; s_keep[1] = ku[1];
                    s_keep[2] = ku[2]; s_keep[3] = ku[3];
                    s_kept = k;
                }
            }
            __syncthreads();
            int prevkept = kept;
            kept = s_kept;

            // extraction: slot = prevkept + prefix-popcount (pop order)
            if (tid < C) {
                int w = tid >> 5, bp = tid & 31;
                unsigned int kw = s_keep[w];
                if ((kw >> bp) & 1u) {
                    int pre = __popc(kw & ((1u << bp) - 1u));
                    for (int q = 0; q < w; ++q) pre += __popc(s_keep[q]);
                    int slot = prevkept + pre;
                    float4 bb = s_bbox[base + tid];
                    s_klist[slot][0] = bb.x; s_klist[slot][1] = bb.y;
                    s_klist[slot][2] = bb.z; s_klist[slot][3] = bb.w;
                    s_klist[slot][4] = __uint_as_float(
                        (unsigned int)(s_sorted[base + tid] >> 32));
                    s_kbox[slot]  = bb;
                    s_karea[slot] = (bb.z - bb.x) * (bb.w - bb.y);
                }
            }
            __syncthreads();
            base += C;
        }

        done = (kept >= MAX_OUT) || (cbin == 0);
        hi = cbin;
    }

    __syncthreads();
    // ---- write all 500 outputs (d_out poisoned each call) ----
    for (int j = tid; j < 4 * MAX_OUT + MAX_OUT; j += 256) {
        float val = 0.0f;
        if (j < 4 * MAX_OUT) {
            int k = j >> 2, cc = j & 3;
            if (k < kept) {
                float h = s_klist[k][2] - s_klist[k][0];
                float w = s_klist[k][3] - s_klist[k][1];
                if (h > MIN_SZ && w > MIN_SZ) {
                    float scale = (cc == 0 || cc == 2) ? img_h : img_w;
                    val = s_klist[k][cc] / scale;
                }
            }
        } else {
            int k = j - 4 * MAX_OUT;
            if (k < kept) {
                float h = s_klist[k][2] - s_klist[k][0];
                float w = s_klist[k][3] - s_klist[k][1];
                if (h > MIN_SZ && w > MIN_SZ) val = s_klist[k][4];
            }
        }
        out[j] = val;
    }
}

extern "C" void kernel_launch(void* const* d_in, const int* in_sizes, int n_in,
                              void* d_out, int out_size, void* d_ws, size_t ws_size,
                              hipStream_t stream) {
    const float* proposals = (const float*)d_in[0];   // [N,4] yxyx pixels
    const float* cls       = (const float*)d_in[1];   // [N,2] logits
    const int*   ph        = (const int*)d_in[2];     // image_h (scalar)
    const int*   pw        = (const int*)d_in[3];     // image_w (scalar)
    float*       out       = (float*)d_out;           // 400 boxes + 100 scores

    int N = in_sizes[0] / 4;
    if (N > N_CAP) N = N_CAP;   // fixed-shape problem; defensive clamp

    // ws: bucket u64[1024*64] (512KB) | hist u32[HIST_WORDS]
    char* ws = (char*)d_ws;
    unsigned long long* bucket = (unsigned long long*)ws;
    unsigned int* hist = (unsigned int*)(ws + (size_t)BUCKET_NB * BCAP * 8);

    zero_hist_kernel<<<(HIST_WORDS + 255) / 256, 256, 0, stream>>>(hist);
    score_kernel<<<(N / 2 + 255) / 256, 256, 0, stream>>>(
        (const float4*)cls, hist, bucket, N);
    select_kernel<<<1, 256, 0, stream>>>(
        (const float4*)proposals, (const float4*)cls, hist, bucket,
        ph, pw, out, N);
}